// Round 1
// baseline (923.074 us; speedup 1.0000x reference)
//
#include <hip/hip_runtime.h>
#include <hip/hip_bf16.h>
#include <stdint.h>

#define NN   4096
#define HIDN 256
#define NHD  8
#define HD   32

typedef __attribute__((ext_vector_type(8))) short short8;
typedef __attribute__((ext_vector_type(4))) float f32x4;

static __device__ __forceinline__ unsigned short f2bf(float f) {
  __hip_bfloat16 h = __float2bfloat16(f);
  return __builtin_bit_cast(unsigned short, h);
}
static __device__ __forceinline__ float bf2f(unsigned short u) {
  __hip_bfloat16 h = __builtin_bit_cast(__hip_bfloat16, u);
  return __bfloat162float(h);
}

// ---------------------------------------------------------------------------
// Kernel 1: Q = (x@Wq^T + bq) * (log2e/sqrt(32)) ; V = x@Wv^T + bv
// Written as bf16 hi/lo splits (row-major [N][256]) + single-bf16 V^T [256][N].
// fp32 vector FMA; x loads are block-uniform (scalar path), W rows per-thread.
// ---------------------------------------------------------------------------
__global__ __launch_bounds__(256) void mhg_qv_kernel(
    const float* __restrict__ x,
    const float* __restrict__ wq_w, const float* __restrict__ wq_b,
    const float* __restrict__ wv_w, const float* __restrict__ wv_b,
    unsigned short* __restrict__ Qhi, unsigned short* __restrict__ Qlo,
    unsigned short* __restrict__ Vhi, unsigned short* __restrict__ Vlo,
    unsigned short* __restrict__ Vt)
{
  const int o  = threadIdx.x;        // output column 0..255
  const int r0 = blockIdx.x * 8;     // 8 rows per block
  float aq[8], av[8];
#pragma unroll
  for (int r = 0; r < 8; ++r) { aq[r] = 0.f; av[r] = 0.f; }
  const float4* wq4 = (const float4*)(wq_w + (size_t)o * HIDN);
  const float4* wv4 = (const float4*)(wv_w + (size_t)o * HIDN);
  const float* xb = x + (size_t)r0 * HIDN;
  for (int k0 = 0; k0 < HIDN / 4; ++k0) {
    float4 wq = wq4[k0];
    float4 wv = wv4[k0];
#pragma unroll
    for (int r = 0; r < 8; ++r) {
      float4 xv = *(const float4*)(xb + r * HIDN + k0 * 4);
      aq[r] = fmaf(xv.x, wq.x, fmaf(xv.y, wq.y, fmaf(xv.z, wq.z, fmaf(xv.w, wq.w, aq[r]))));
      av[r] = fmaf(xv.x, wv.x, fmaf(xv.y, wv.y, fmaf(xv.z, wv.z, fmaf(xv.w, wv.w, av[r]))));
    }
  }
  const float bq = wq_b[o], bv = wv_b[o];
  constexpr float CS = (float)(1.4426950408889634 / 5.656854249492380195206754896838);
  alignas(16) unsigned short vt8[8];
#pragma unroll
  for (int r = 0; r < 8; ++r) {
    float qv = (aq[r] + bq) * CS;             // prescale: exp(s/sqrt(32)) == exp2(q_scaled . v)
    unsigned short qh = f2bf(qv);
    unsigned short ql = f2bf(qv - bf2f(qh));  // 2-term split: ~2^-17 relative
    float vv = av[r] + bv;
    unsigned short vh = f2bf(vv);
    unsigned short vl = f2bf(vv - bf2f(vh));
    size_t idx = (size_t)(r0 + r) * HIDN + o;
    Qhi[idx] = qh; Qlo[idx] = ql;
    Vhi[idx] = vh; Vlo[idx] = vl;
    vt8[r] = vh;                              // thread already owns column o of all 8 rows
  }
  *(uint4*)(Vt + (size_t)o * NN + r0) = *(const uint4*)vt8;  // V^T, 16B coalesced-ish store
}

// ---------------------------------------------------------------------------
// Kernel 2: fused scores -> softmax -> attn write + O accumulate.
// One wave (64 thr) per (head, 16-row group). MFMA 16x16x32 bf16, K=32=head dim.
// A-frag: A[m=lane&15][k=quad*8+j]; B-frag: B[k=quad*8+j][n=lane&15];
// C/D: col=lane&15, row=quad*4+reg  (per guide §3, m89/m120 verified).
// Pass A: l[row] = sum over cols of exp2(s2) for unmasked cols (no max needed:
//         s2 ~ N(0,~2), |s2| < ~10, exp2 cannot overflow fp32).
//         Adj mask cached as ballot bits in LDS (one 64b word per chunk/reg).
// Pass B: attn = exp2(s2)/l (masked -> 0), written fp32; P -> LDS -> A-frag ->
//         O += P@V via MFMA with B from V^T.
// ---------------------------------------------------------------------------
__global__ __launch_bounds__(64) void mhg_attn_kernel(
    const int* __restrict__ Adj,
    const unsigned short* __restrict__ Qhi, const unsigned short* __restrict__ Qlo,
    const unsigned short* __restrict__ Vhi, const unsigned short* __restrict__ Vlo,
    const unsigned short* __restrict__ Vt,
    float* __restrict__ attn, float* __restrict__ O)
{
  const int lane = threadIdx.x & 63;
  const int n    = lane & 15;        // tile column (and A-frag row m)
  const int qd   = lane >> 4;        // quad
  const int h    = blockIdx.x & (NHD - 1);   // head -> XCD-affine (bx % 8)
  const int rb   = blockIdx.x >> 3;
  const int wr0  = rb * 16;

  __shared__ uint64_t maskB[256][4];                 // 8 KB: ballot mask per (chunk, reg)
  __shared__ __align__(16) unsigned short Plds[16][40];  // P tile 16x32 bf16, +8 pad

  const size_t hoff = (size_t)h * HD + qd * 8;
  const short8 a_hi = *(const short8*)(Qhi + (size_t)(wr0 + n) * HIDN + hoff);
  const short8 a_lo = *(const short8*)(Qlo + (size_t)(wr0 + n) * HIDN + hoff);
  const unsigned short* pVh = Vhi + (size_t)n * HIDN + hoff;
  const unsigned short* pVl = Vlo + (size_t)n * HIDN + hoff;
  const size_t adjb = (size_t)(wr0 + 4 * qd) * NN + n;

  float l0 = 0.f, l1 = 0.f, l2 = 0.f, l3 = 0.f;

  // ---- pass A (software-pipelined one chunk ahead) ----
  short8 bh = *(const short8*)(pVh);
  short8 bl = *(const short8*)(pVl);
  int a0 = Adj[adjb], a1 = Adj[adjb + NN], a2 = Adj[adjb + 2 * NN], a3 = Adj[adjb + 3 * NN];

  for (int c = 0; c < 256; ++c) {
    const int cn = (c < 255) ? c + 1 : 255;
    short8 bhn = *(const short8*)(pVh + (size_t)cn * (16 * HIDN));
    short8 bln = *(const short8*)(pVl + (size_t)cn * (16 * HIDN));
    const size_t ab = adjb + (size_t)cn * 16;
    int a0n = Adj[ab], a1n = Adj[ab + NN], a2n = Adj[ab + 2 * NN], a3n = Adj[ab + 3 * NN];

    f32x4 acc = {0.f, 0.f, 0.f, 0.f};
    acc = __builtin_amdgcn_mfma_f32_16x16x32_bf16(a_hi, bh, acc, 0, 0, 0);
    acc = __builtin_amdgcn_mfma_f32_16x16x32_bf16(a_lo, bh, acc, 0, 0, 0);
    acc = __builtin_amdgcn_mfma_f32_16x16x32_bf16(a_hi, bl, acc, 0, 0, 0);

    uint64_t m0 = __ballot(a0 != 0);
    uint64_t m1 = __ballot(a1 != 0);
    uint64_t m2 = __ballot(a2 != 0);
    uint64_t m3 = __ballot(a3 != 0);
    if (lane == 0) { maskB[c][0] = m0; maskB[c][1] = m1; maskB[c][2] = m2; maskB[c][3] = m3; }

    l0 += a0 ? __builtin_amdgcn_exp2f(acc[0]) : 0.f;
    l1 += a1 ? __builtin_amdgcn_exp2f(acc[1]) : 0.f;
    l2 += a2 ? __builtin_amdgcn_exp2f(acc[2]) : 0.f;
    l3 += a3 ? __builtin_amdgcn_exp2f(acc[3]) : 0.f;

    bh = bhn; bl = bln; a0 = a0n; a1 = a1n; a2 = a2n; a3 = a3n;
  }

  // row sums live across the 16 lanes of each quad group -> butterfly within width 16
  float r0v, r1v, r2v, r3v;
  {
    float s;
    s = l0; s += __shfl_xor(s, 1, 16); s += __shfl_xor(s, 2, 16); s += __shfl_xor(s, 4, 16); s += __shfl_xor(s, 8, 16); r0v = 1.0f / s;
    s = l1; s += __shfl_xor(s, 1, 16); s += __shfl_xor(s, 2, 16); s += __shfl_xor(s, 4, 16); s += __shfl_xor(s, 8, 16); r1v = 1.0f / s;
    s = l2; s += __shfl_xor(s, 1, 16); s += __shfl_xor(s, 2, 16); s += __shfl_xor(s, 4, 16); s += __shfl_xor(s, 8, 16); r2v = 1.0f / s;
    s = l3; s += __shfl_xor(s, 1, 16); s += __shfl_xor(s, 2, 16); s += __shfl_xor(s, 4, 16); s += __shfl_xor(s, 8, 16); r3v = 1.0f / s;
  }

  // ---- pass B ----
  f32x4 oc0 = {0.f, 0.f, 0.f, 0.f}, oc1 = {0.f, 0.f, 0.f, 0.f};
  const unsigned short* pVt0 = Vt + (size_t)(h * HD + n) * NN + qd * 8;  // dims 0..15 of head
  const unsigned short* pVt1 = pVt0 + (size_t)16 * NN;                   // dims 16..31
  float* pAt = attn + (size_t)h * NN * NN + (size_t)(wr0 + 4 * qd) * NN + n;

  short8 bh0 = *(const short8*)(pVh);
  short8 bl0 = *(const short8*)(pVl);
  short8 bh1 = *(const short8*)(pVh + 16 * HIDN);
  short8 bl1 = *(const short8*)(pVl + 16 * HIDN);
  short8 vb0 = *(const short8*)(pVt0);
  short8 vb1 = *(const short8*)(pVt1);

  for (int cp = 0; cp < 128; ++cp) {
    const int np = (cp < 127) ? cp + 1 : 127;
    short8 bh0n = *(const short8*)(pVh + (size_t)(2 * np) * (16 * HIDN));
    short8 bl0n = *(const short8*)(pVl + (size_t)(2 * np) * (16 * HIDN));
    short8 bh1n = *(const short8*)(pVh + (size_t)(2 * np + 1) * (16 * HIDN));
    short8 bl1n = *(const short8*)(pVl + (size_t)(2 * np + 1) * (16 * HIDN));
    short8 vb0n = *(const short8*)(pVt0 + (size_t)np * 32);
    short8 vb1n = *(const short8*)(pVt1 + (size_t)np * 32);

    {   // even chunk
      const int c = 2 * cp;
      const size_t c0 = (size_t)c * 16;
      f32x4 acc = {0.f, 0.f, 0.f, 0.f};
      acc = __builtin_amdgcn_mfma_f32_16x16x32_bf16(a_hi, bh0, acc, 0, 0, 0);
      acc = __builtin_amdgcn_mfma_f32_16x16x32_bf16(a_lo, bh0, acc, 0, 0, 0);
      acc = __builtin_amdgcn_mfma_f32_16x16x32_bf16(a_hi, bl0, acc, 0, 0, 0);
      uint64_t m0 = maskB[c][0], m1 = maskB[c][1], m2 = maskB[c][2], m3 = maskB[c][3];
      float p0 = ((m0 >> lane) & 1) ? __builtin_amdgcn_exp2f(acc[0]) * r0v : 0.f;
      float p1 = ((m1 >> lane) & 1) ? __builtin_amdgcn_exp2f(acc[1]) * r1v : 0.f;
      float p2 = ((m2 >> lane) & 1) ? __builtin_amdgcn_exp2f(acc[2]) * r2v : 0.f;
      float p3 = ((m3 >> lane) & 1) ? __builtin_amdgcn_exp2f(acc[3]) * r3v : 0.f;
      pAt[c0] = p0; pAt[c0 + NN] = p1; pAt[c0 + 2 * NN] = p2; pAt[c0 + 3 * NN] = p3;
      Plds[4 * qd + 0][n] = f2bf(p0);
      Plds[4 * qd + 1][n] = f2bf(p1);
      Plds[4 * qd + 2][n] = f2bf(p2);
      Plds[4 * qd + 3][n] = f2bf(p3);
    }
    {   // odd chunk
      const int c = 2 * cp + 1;
      const size_t c0 = (size_t)c * 16;
      f32x4 acc = {0.f, 0.f, 0.f, 0.f};
      acc = __builtin_amdgcn_mfma_f32_16x16x32_bf16(a_hi, bh1, acc, 0, 0, 0);
      acc = __builtin_amdgcn_mfma_f32_16x16x32_bf16(a_lo, bh1, acc, 0, 0, 0);
      acc = __builtin_amdgcn_mfma_f32_16x16x32_bf16(a_hi, bl1, acc, 0, 0, 0);
      uint64_t m0 = maskB[c][0], m1 = maskB[c][1], m2 = maskB[c][2], m3 = maskB[c][3];
      float p0 = ((m0 >> lane) & 1) ? __builtin_amdgcn_exp2f(acc[0]) * r0v : 0.f;
      float p1 = ((m1 >> lane) & 1) ? __builtin_amdgcn_exp2f(acc[1]) * r1v : 0.f;
      float p2 = ((m2 >> lane) & 1) ? __builtin_amdgcn_exp2f(acc[2]) * r2v : 0.f;
      float p3 = ((m3 >> lane) & 1) ? __builtin_amdgcn_exp2f(acc[3]) * r3v : 0.f;
      pAt[c0] = p0; pAt[c0 + NN] = p1; pAt[c0 + 2 * NN] = p2; pAt[c0 + 3 * NN] = p3;
      Plds[4 * qd + 0][16 + n] = f2bf(p0);
      Plds[4 * qd + 1][16 + n] = f2bf(p1);
      Plds[4 * qd + 2][16 + n] = f2bf(p2);
      Plds[4 * qd + 3][16 + n] = f2bf(p3);
    }
    // LDS RAW: same-wave only. Compiler fence + lgkmcnt(0) drain, then read A-frag.
    __asm__ volatile("" ::: "memory");
    __builtin_amdgcn_s_waitcnt(0xC07F);   // vmcnt=63, expcnt=7, lgkmcnt=0
    __asm__ volatile("" ::: "memory");
    short8 ap = *(const short8*)&Plds[n][qd * 8];
    oc0 = __builtin_amdgcn_mfma_f32_16x16x32_bf16(ap, vb0, oc0, 0, 0, 0);
    oc1 = __builtin_amdgcn_mfma_f32_16x16x32_bf16(ap, vb1, oc1, 0, 0, 0);

    bh0 = bh0n; bl0 = bl0n; bh1 = bh1n; bl1 = bl1n; vb0 = vb0n; vb1 = vb1n;
  }

  const int orow = wr0 + 4 * qd;
#pragma unroll
  for (int r = 0; r < 4; ++r) {
    O[(size_t)(orow + r) * HIDN + h * HD + n]      = oc0[r];
    O[(size_t)(orow + r) * HIDN + h * HD + 16 + n] = oc1[r];
  }
}

// ---------------------------------------------------------------------------
// Kernel 3: out = O @ Wo^T + bo  (fp32 vector)
// ---------------------------------------------------------------------------
__global__ __launch_bounds__(256) void mhg_oproj_kernel(
    const float* __restrict__ O,
    const float* __restrict__ wo_w, const float* __restrict__ wo_b,
    float* __restrict__ out)
{
  const int o  = threadIdx.x;
  const int r0 = blockIdx.x * 8;
  float ac[8];
#pragma unroll
  for (int r = 0; r < 8; ++r) ac[r] = 0.f;
  const float4* wo4 = (const float4*)(wo_w + (size_t)o * HIDN);
  const float* Ob = O + (size_t)r0 * HIDN;
  for (int k0 = 0; k0 < HIDN / 4; ++k0) {
    float4 w = wo4[k0];
#pragma unroll
    for (int r = 0; r < 8; ++r) {
      float4 xv = *(const float4*)(Ob + r * HIDN + k0 * 4);
      ac[r] = fmaf(xv.x, w.x, fmaf(xv.y, w.y, fmaf(xv.z, w.z, fmaf(xv.w, w.w, ac[r]))));
    }
  }
  const float b = wo_b[o];
#pragma unroll
  for (int r = 0; r < 8; ++r)
    out[(size_t)(r0 + r) * HIDN + o] = ac[r] + b;
}

extern "C" void kernel_launch(void* const* d_in, const int* in_sizes, int n_in,
                              void* d_out, int out_size, void* d_ws, size_t ws_size,
                              hipStream_t stream) {
  (void)in_sizes; (void)n_in; (void)out_size; (void)ws_size;
  const float* x    = (const float*)d_in[0];
  const int*   Adj  = (const int*)d_in[1];
  const float* wq_w = (const float*)d_in[2];
  const float* wq_b = (const float*)d_in[3];
  // d_in[4], d_in[5] = wk_w / wk_b : computed-but-unused in reference (the bug) -> skipped
  const float* wv_w = (const float*)d_in[6];
  const float* wv_b = (const float*)d_in[7];
  const float* wo_w = (const float*)d_in[8];
  const float* wo_b = (const float*)d_in[9];

  float* out  = (float*)d_out;                       // output 0: [4096,256]
  float* attn = out + (size_t)NN * HIDN;             // output 1: [8,4096,4096]

  // workspace layout (14 MB total)
  unsigned short* Qhi = (unsigned short*)d_ws;
  unsigned short* Qlo = Qhi + (size_t)NN * HIDN;
  unsigned short* Vhi = Qlo + (size_t)NN * HIDN;
  unsigned short* Vlo = Vhi + (size_t)NN * HIDN;
  unsigned short* Vt  = Vlo + (size_t)NN * HIDN;
  float*          Oacc = (float*)(Vt + (size_t)NN * HIDN);

  hipLaunchKernelGGL(mhg_qv_kernel, dim3(NN / 8), dim3(256), 0, stream,
                     x, wq_w, wq_b, wv_w, wv_b, Qhi, Qlo, Vhi, Vlo, Vt);
  hipLaunchKernelGGL(mhg_attn_kernel, dim3(NHD * (NN / 16)), dim3(64), 0, stream,
                     Adj, Qhi, Qlo, Vhi, Vlo, Vt, attn, Oacc);
  hipLaunchKernelGGL(mhg_oproj_kernel, dim3(NN / 8), dim3(256), 0, stream,
                     Oacc, wo_w, wo_b, out);
}